// Round 6
// baseline (2220.211 us; speedup 1.0000x reference)
//
#include <hip/hip_runtime.h>
#include <cstdint>
#include <cstddef>

// DIAGNOSTIC ROUND 2: kernel bodies identical to round 4, but spmm kernels
// take a REP template (in-kernel idempotent repeat) sized to push their
// dispatch duration past the ~645us harness fills so rocprof's top-5 finally
// shows per-kernel counters: S1 REP=3 (~3*T_S1), S2 REP=8 (~8*T_S2).
// Round-5 established T_S1+T_S2+T_S3 = 638.8us, rest = 51us; this round
// splits that sum and diagnoses the limiter (BW vs latency vs VALU).
//
// GCN via associativity: relu((A@H)@W^T) == relu(A@(H@W^T)).
// Per layer: tiny proj PT=(H W^T)^T (bf16, k-slot-permuted) + split-K
// tall-skinny MFMA GEMM part=A@P. S1 streams fp32 A once (nt), saves bf16 A
// as MFMA-fragment tiles [rowgrp][kblk][lane][8] (1KB-dense, cached).

#define NN 16384
#define SK1 8
#define KC1 (NN / SK1)   // 2048
#define SK2 16
#define KC2 (NN / SK2)   // 1024
#define NKB (NN / 32)    // 512 k-blocks

typedef __attribute__((ext_vector_type(8))) short s16x8;
typedef __attribute__((ext_vector_type(4))) float fx4;

__device__ __forceinline__ unsigned short f2bf_rne(float f) {
    unsigned int x = __builtin_bit_cast(unsigned int, f);
    x += 0x7fffu + ((x >> 16) & 1u);
    return (unsigned short)(x >> 16);
}

__device__ __forceinline__ s16x8 pack_bf(fx4 a, fx4 b) {
    s16x8 t;
    t[0] = (short)f2bf_rne(a[0]);
    t[1] = (short)f2bf_rne(a[1]);
    t[2] = (short)f2bf_rne(a[2]);
    t[3] = (short)f2bf_rne(a[3]);
    t[4] = (short)f2bf_rne(b[0]);
    t[5] = (short)f2bf_rne(b[1]);
    t[6] = (short)f2bf_rne(b[2]);
    t[7] = (short)f2bf_rne(b[3]);
    return t;
}

// ---------------------------------------------------------------------------
// S1: part[s] = A@P1 (D=64). fp32 A (nt) -> bf16 frag-tiled copy (cached).
// ---------------------------------------------------------------------------
template <int SAVE, int REP>
__global__ __launch_bounds__(256, 4) void k_spmm1(
    const float* __restrict__ A32,
    unsigned short* __restrict__ Abf,        // [NN/16][NKB][64][8] bf16 tiles
    const unsigned short* __restrict__ PT,   // [64][NN] bf16, slot-permuted
    float* __restrict__ part)                // [SK1][NN][64] f32
{
    const int lane = threadIdx.x & 63;
    const int wv   = threadIdx.x >> 6;
    const int srow = lane & 15;
    const int kg   = lane >> 4;
    const int s    = blockIdx.y;
    const long kbeg = (long)s * KC1;
    const int rowbase = blockIdx.x * 128 + wv * 32;
    const long r0 = rowbase + srow;
    const long r1 = rowbase + 16 + srow;
    const long g0 = rowbase >> 4, g1 = g0 + 1;

    for (int rep = 0; rep < REP; ++rep) {
        fx4 acc0[4], acc1[4];
#pragma unroll
        for (int c = 0; c < 4; ++c) {
            acc0[c] = (fx4){0.f, 0.f, 0.f, 0.f};
            acc1[c] = (fx4){0.f, 0.f, 0.f, 0.f};
        }

#pragma unroll 2
        for (int i = 0; i < KC1 / 32; ++i) {
            const long ko = kbeg + (long)i * 32;
            const long kblk = ko >> 5;
            const float* p0 = A32 + r0 * (long)NN + ko + kg * 4;
            const float* p1 = A32 + r1 * (long)NN + ko + kg * 4;
            fx4 a00 = __builtin_nontemporal_load((const fx4*)p0);
            fx4 a01 = __builtin_nontemporal_load((const fx4*)(p0 + 16));
            fx4 a10 = __builtin_nontemporal_load((const fx4*)p1);
            fx4 a11 = __builtin_nontemporal_load((const fx4*)(p1 + 16));
            s16x8 af0 = pack_bf(a00, a01);
            s16x8 af1 = pack_bf(a10, a11);
            if (SAVE) {
                *(s16x8*)(Abf + ((g0 * NKB + kblk) * 64 + lane) * 8) = af0;
                *(s16x8*)(Abf + ((g1 * NKB + kblk) * 64 + lane) * 8) = af1;
            }
#pragma unroll
            for (int c = 0; c < 4; ++c) {
                s16x8 bf = *(const s16x8*)(PT + (long)(c * 16 + srow) * NN + ko + kg * 8);
                acc0[c] = __builtin_amdgcn_mfma_f32_16x16x32_bf16(af0, bf, acc0[c], 0, 0, 0);
                acc1[c] = __builtin_amdgcn_mfma_f32_16x16x32_bf16(af1, bf, acc1[c], 0, 0, 0);
            }
        }
        // C layout: col = lane&15, row = (lane>>4)*4 + reg
        float* pbase = part + (long)s * NN * 64;
#pragma unroll
        for (int c = 0; c < 4; ++c)
#pragma unroll
            for (int r = 0; r < 4; ++r) {
                pbase[(long)(rowbase + kg * 4 + r) * 64 + c * 16 + srow]      = acc0[c][r];
                pbase[(long)(rowbase + 16 + kg * 4 + r) * 64 + c * 16 + srow] = acc1[c][r];
            }
    }
}

// ---------------------------------------------------------------------------
// S2/S3: part[s] = A@P (D=32). 4 row-tiles/wave, frag-tiled bf16 A.
// ---------------------------------------------------------------------------
template <int ABF, int REP>
__global__ __launch_bounds__(256, 4) void k_spmm2(
    const unsigned short* __restrict__ Abf,
    const float* __restrict__ A32,
    const unsigned short* __restrict__ PT,   // [32][NN]
    float* __restrict__ part)                // [SK2][NN][32]
{
    const int lane = threadIdx.x & 63;
    const int wv   = threadIdx.x >> 6;
    const int srow = lane & 15;
    const int kg   = lane >> 4;
    const int s    = blockIdx.y;
    const long kbeg = (long)s * KC2;
    const int rowbase = blockIdx.x * 256 + wv * 64;
    const long g0 = rowbase >> 4;

    for (int rep = 0; rep < REP; ++rep) {
        fx4 acc[4][2];
#pragma unroll
        for (int t = 0; t < 4; ++t)
#pragma unroll
            for (int c = 0; c < 2; ++c) acc[t][c] = (fx4){0.f, 0.f, 0.f, 0.f};

#pragma unroll 2
        for (int i = 0; i < KC2 / 32; ++i) {
            const long ko = kbeg + (long)i * 32;
            const long kblk = ko >> 5;
            s16x8 af[4];
            if (ABF) {
#pragma unroll
                for (int t = 0; t < 4; ++t)
                    af[t] = *(const s16x8*)(Abf + (((g0 + t) * NKB + kblk) * 64 + lane) * 8);
            } else {
#pragma unroll
                for (int t = 0; t < 4; ++t) {
                    const float* p = A32 + (long)(rowbase + t * 16 + srow) * NN + ko + kg * 4;
                    fx4 a0 = __builtin_nontemporal_load((const fx4*)p);
                    fx4 a1 = __builtin_nontemporal_load((const fx4*)(p + 16));
                    af[t] = pack_bf(a0, a1);
                }
            }
            s16x8 b0 = *(const s16x8*)(PT + (long)srow * NN + ko + kg * 8);
            s16x8 b1 = *(const s16x8*)(PT + (long)(16 + srow) * NN + ko + kg * 8);
#pragma unroll
            for (int t = 0; t < 4; ++t) {
                acc[t][0] = __builtin_amdgcn_mfma_f32_16x16x32_bf16(af[t], b0, acc[t][0], 0, 0, 0);
                acc[t][1] = __builtin_amdgcn_mfma_f32_16x16x32_bf16(af[t], b1, acc[t][1], 0, 0, 0);
            }
        }
        float* pbase = part + (long)s * NN * 32;
#pragma unroll
        for (int t = 0; t < 4; ++t)
#pragma unroll
            for (int c = 0; c < 2; ++c)
#pragma unroll
                for (int r = 0; r < 4; ++r)
                    pbase[(long)(rowbase + t * 16 + kg * 4 + r) * 32 + c * 16 + srow] = acc[t][c][r];
    }
}

// ---------------------------------------------------------------------------
// Projection: PT[c][perm(r)] = bf16( act(H[r,:]) @ W[c,:] )
// ---------------------------------------------------------------------------
template <int DIN, int DOUT, int NSUM, bool RELU>
__global__ __launch_bounds__(256) void k_proj(
    const float* __restrict__ src,     // [NSUM][NN][DIN]
    const float* __restrict__ W,       // [DOUT][DIN]
    unsigned short* __restrict__ PT)   // [DOUT][NN] slot-permuted
{
    __shared__ float Ws[DOUT * DIN];
    __shared__ float Hs[64][DIN + 1];
    const int tid = threadIdx.x;
    for (int i = tid; i < DOUT * DIN; i += 256) Ws[i] = W[i];
    const int rbase = blockIdx.x * 64;
    for (int i = tid; i < 64 * DIN; i += 256) {
        const int rl = i / DIN, k = i % DIN;
        float v = 0.f;
#pragma unroll
        for (int s2 = 0; s2 < NSUM; ++s2)
            v += src[(long)s2 * NN * DIN + (long)(rbase + rl) * DIN + k];
        Hs[rl][k] = RELU ? fmaxf(v, 0.f) : v;
    }
    __syncthreads();
    const int rl = tid & 63;
    const int c0 = tid >> 6;
    const int r  = rbase + rl;
    const int kk = r & 31;
    const int pidx = (r & ~31) + ((kk & 15) >> 2) * 8 + (kk & 3) + ((kk >> 4) << 2);
    for (int c = c0; c < DOUT; c += 4) {
        float accv = 0.f;
#pragma unroll
        for (int k = 0; k < DIN; ++k) accv += Hs[rl][k] * Ws[c * DIN + k];
        PT[(long)c * NN + pidx] = f2bf_rne(accv);
    }
}

// Final reduce: out[NN][32] = sum_s part[s]
__global__ __launch_bounds__(256) void k_red(
    const float* __restrict__ part, float* __restrict__ out)
{
    const int e = blockIdx.x * 256 + threadIdx.x;
    if (e >= NN * 32 / 4) return;
    fx4 v = (fx4){0.f, 0.f, 0.f, 0.f};
#pragma unroll
    for (int s = 0; s < SK2; ++s)
        v += *(const fx4*)(part + (long)s * NN * 32 + (long)e * 4);
    *(fx4*)(out + (long)e * 4) = v;
}

extern "C" void kernel_launch(void* const* d_in, const int* in_sizes, int n_in,
                              void* d_out, int out_size, void* d_ws, size_t ws_size,
                              hipStream_t stream) {
    const float* A  = (const float*)d_in[0];
    const float* X  = (const float*)d_in[1];
    const float* W1 = (const float*)d_in[2];
    const float* W2 = (const float*)d_in[3];
    const float* W3 = (const float*)d_in[4];
    float* out = (float*)d_out;

    char* ws = (char*)d_ws;
    const size_t part_b = (size_t)SK1 * NN * 64 * 4;   // 32 MiB (== SK2*NN*32*4)
    const size_t pt_b   = (size_t)64 * NN * 2;         //  2 MiB
    const size_t abf_b  = (size_t)NN * NN * 2;         // 512 MiB
    float*          part = (float*)ws;
    unsigned short* PT   = (unsigned short*)(ws + part_b);
    unsigned short* Abf  = (unsigned short*)(ws + part_b + pt_b);
    const bool save = ws_size >= part_b + pt_b + abf_b;

    dim3 b(256);
    dim3 gP(NN / 64);
    dim3 g1(NN / 128, SK1);
    dim3 g2(NN / 256, SK2);

    // Layer 1  (S1 REP=3: diagnostic, idempotent -> ~3*T_S1 dispatch)
    k_proj<64, 64, 1, false><<<gP, b, 0, stream>>>(X, W1, PT);
    if (save) k_spmm1<1, 3><<<g1, b, 0, stream>>>(A, Abf, PT, part);
    else      k_spmm1<0, 3><<<g1, b, 0, stream>>>(A, Abf, PT, part);

    // Layer 2  (S2 REP=8 -> ~8*T_S2 dispatch)
    k_proj<64, 32, SK1, true><<<gP, b, 0, stream>>>(part, W2, PT);
    if (save) k_spmm2<1, 8><<<g2, b, 0, stream>>>(Abf, A, PT, part);
    else      k_spmm2<0, 8><<<g2, b, 0, stream>>>(Abf, A, PT, part);

    // Layer 3  (S3 normal)
    k_proj<32, 32, SK2, true><<<gP, b, 0, stream>>>(part, W3, PT);
    if (save) k_spmm2<1, 1><<<g2, b, 0, stream>>>(Abf, A, PT, part);
    else      k_spmm2<0, 1><<<g2, b, 0, stream>>>(Abf, A, PT, part);

    k_red<<<dim3(NN * 32 / 4 / 256), b, 0, stream>>>(part, out);
}

// Round 7
// 847.573 us; speedup vs baseline: 2.6195x; 2.6195x over previous
//
#include <hip/hip_runtime.h>
#include <cstdint>
#include <cstddef>

// GCN via associativity: relu((A@H)@W^T) == relu(A@(H@W^T)).
// Per layer: tiny proj PT=(H W^T)^T (bf16, k-slot-permuted) + split-K
// tall-skinny MFMA GEMM part=A@P. S1 streams fp32 A once, saves bf16 A as
// MFMA-fragment tiles [rowgrp][kblk][lane][8] (1KB-dense); S2/S3 stream the
// bf16 copy (L3 serves a large fraction per round-3 counters).
//
// Round-6 attribution: T_S1=425us (mem-wait: MfmaUtil 3.3/VALU 5.8/Occ 37%),
// T_S2=T_S3=97us (near mixed-stream ceiling), rest=51us.
// Round-7 levers (S1 only): occupancy 4->8 blocks/CU (SK1=16, bounds(256,8))
// + drop nt from A loads (plain loads = measured 6.4TB/s path).

#define NN 16384
#define SK1 16
#define KC1 (NN / SK1)   // 1024
#define SK2 16
#define KC2 (NN / SK2)   // 1024
#define NKB (NN / 32)    // 512 k-blocks

typedef __attribute__((ext_vector_type(8))) short s16x8;
typedef __attribute__((ext_vector_type(4))) float fx4;

__device__ __forceinline__ unsigned short f2bf_rne(float f) {
    unsigned int x = __builtin_bit_cast(unsigned int, f);
    x += 0x7fffu + ((x >> 16) & 1u);
    return (unsigned short)(x >> 16);
}

__device__ __forceinline__ s16x8 pack_bf(fx4 a, fx4 b) {
    s16x8 t;
    t[0] = (short)f2bf_rne(a[0]);
    t[1] = (short)f2bf_rne(a[1]);
    t[2] = (short)f2bf_rne(a[2]);
    t[3] = (short)f2bf_rne(a[3]);
    t[4] = (short)f2bf_rne(b[0]);
    t[5] = (short)f2bf_rne(b[1]);
    t[6] = (short)f2bf_rne(b[2]);
    t[7] = (short)f2bf_rne(b[3]);
    return t;
}

// ---------------------------------------------------------------------------
// S1: part[s] = A@P1 (D=64). fp32 A (plain loads) -> bf16 frag-tiled copy.
// 2 row-tiles/wave. grid (NN/128, SK1) = 2048 blocks -> 8 blocks/CU.
// ---------------------------------------------------------------------------
template <int SAVE>
__global__ __launch_bounds__(256, 8) void k_spmm1(
    const float* __restrict__ A32,
    unsigned short* __restrict__ Abf,        // [NN/16][NKB][64][8] bf16 tiles
    const unsigned short* __restrict__ PT,   // [64][NN] bf16, slot-permuted
    float* __restrict__ part)                // [SK1][NN][64] f32
{
    const int lane = threadIdx.x & 63;
    const int wv   = threadIdx.x >> 6;
    const int srow = lane & 15;
    const int kg   = lane >> 4;
    const int s    = blockIdx.y;
    const long kbeg = (long)s * KC1;
    const int rowbase = blockIdx.x * 128 + wv * 32;
    const long r0 = rowbase + srow;
    const long r1 = rowbase + 16 + srow;
    const long g0 = rowbase >> 4, g1 = g0 + 1;

    fx4 acc0[4], acc1[4];
#pragma unroll
    for (int c = 0; c < 4; ++c) {
        acc0[c] = (fx4){0.f, 0.f, 0.f, 0.f};
        acc1[c] = (fx4){0.f, 0.f, 0.f, 0.f};
    }

#pragma unroll 2
    for (int i = 0; i < KC1 / 32; ++i) {
        const long ko = kbeg + (long)i * 32;
        const long kblk = ko >> 5;
        const float* p0 = A32 + r0 * (long)NN + ko + kg * 4;
        const float* p1 = A32 + r1 * (long)NN + ko + kg * 4;
        fx4 a00 = *(const fx4*)p0;
        fx4 a01 = *(const fx4*)(p0 + 16);
        fx4 a10 = *(const fx4*)p1;
        fx4 a11 = *(const fx4*)(p1 + 16);
        s16x8 af0 = pack_bf(a00, a01);
        s16x8 af1 = pack_bf(a10, a11);
        if (SAVE) {
            *(s16x8*)(Abf + ((g0 * NKB + kblk) * 64 + lane) * 8) = af0;
            *(s16x8*)(Abf + ((g1 * NKB + kblk) * 64 + lane) * 8) = af1;
        }
#pragma unroll
        for (int c = 0; c < 4; ++c) {
            s16x8 bf = *(const s16x8*)(PT + (long)(c * 16 + srow) * NN + ko + kg * 8);
            acc0[c] = __builtin_amdgcn_mfma_f32_16x16x32_bf16(af0, bf, acc0[c], 0, 0, 0);
            acc1[c] = __builtin_amdgcn_mfma_f32_16x16x32_bf16(af1, bf, acc1[c], 0, 0, 0);
        }
    }
    // C layout: col = lane&15, row = (lane>>4)*4 + reg
    float* pbase = part + (long)s * NN * 64;
#pragma unroll
    for (int c = 0; c < 4; ++c)
#pragma unroll
        for (int r = 0; r < 4; ++r) {
            pbase[(long)(rowbase + kg * 4 + r) * 64 + c * 16 + srow]      = acc0[c][r];
            pbase[(long)(rowbase + 16 + kg * 4 + r) * 64 + c * 16 + srow] = acc1[c][r];
        }
}

// ---------------------------------------------------------------------------
// S2/S3: part[s] = A@P (D=32). 4 row-tiles/wave, frag-tiled bf16 A.
// ---------------------------------------------------------------------------
template <int ABF>
__global__ __launch_bounds__(256, 4) void k_spmm2(
    const unsigned short* __restrict__ Abf,
    const float* __restrict__ A32,
    const unsigned short* __restrict__ PT,   // [32][NN]
    float* __restrict__ part)                // [SK2][NN][32]
{
    const int lane = threadIdx.x & 63;
    const int wv   = threadIdx.x >> 6;
    const int srow = lane & 15;
    const int kg   = lane >> 4;
    const int s    = blockIdx.y;
    const long kbeg = (long)s * KC2;
    const int rowbase = blockIdx.x * 256 + wv * 64;
    const long g0 = rowbase >> 4;

    fx4 acc[4][2];
#pragma unroll
    for (int t = 0; t < 4; ++t)
#pragma unroll
        for (int c = 0; c < 2; ++c) acc[t][c] = (fx4){0.f, 0.f, 0.f, 0.f};

#pragma unroll 2
    for (int i = 0; i < KC2 / 32; ++i) {
        const long ko = kbeg + (long)i * 32;
        const long kblk = ko >> 5;
        s16x8 af[4];
        if (ABF) {
#pragma unroll
            for (int t = 0; t < 4; ++t)
                af[t] = *(const s16x8*)(Abf + (((g0 + t) * NKB + kblk) * 64 + lane) * 8);
        } else {
#pragma unroll
            for (int t = 0; t < 4; ++t) {
                const float* p = A32 + (long)(rowbase + t * 16 + srow) * NN + ko + kg * 4;
                fx4 a0 = *(const fx4*)p;
                fx4 a1 = *(const fx4*)(p + 16);
                af[t] = pack_bf(a0, a1);
            }
        }
        s16x8 b0 = *(const s16x8*)(PT + (long)srow * NN + ko + kg * 8);
        s16x8 b1 = *(const s16x8*)(PT + (long)(16 + srow) * NN + ko + kg * 8);
#pragma unroll
        for (int t = 0; t < 4; ++t) {
            acc[t][0] = __builtin_amdgcn_mfma_f32_16x16x32_bf16(af[t], b0, acc[t][0], 0, 0, 0);
            acc[t][1] = __builtin_amdgcn_mfma_f32_16x16x32_bf16(af[t], b1, acc[t][1], 0, 0, 0);
        }
    }
    float* pbase = part + (long)s * NN * 32;
#pragma unroll
    for (int t = 0; t < 4; ++t)
#pragma unroll
        for (int c = 0; c < 2; ++c)
#pragma unroll
            for (int r = 0; r < 4; ++r)
                pbase[(long)(rowbase + t * 16 + kg * 4 + r) * 32 + c * 16 + srow] = acc[t][c][r];
}

// ---------------------------------------------------------------------------
// Projection: PT[c][perm(r)] = bf16( act(H[r,:]) @ W[c,:] )
// ---------------------------------------------------------------------------
template <int DIN, int DOUT, int NSUM, bool RELU>
__global__ __launch_bounds__(256) void k_proj(
    const float* __restrict__ src,     // [NSUM][NN][DIN]
    const float* __restrict__ W,       // [DOUT][DIN]
    unsigned short* __restrict__ PT)   // [DOUT][NN] slot-permuted
{
    __shared__ float Ws[DOUT * DIN];
    __shared__ float Hs[64][DIN + 1];
    const int tid = threadIdx.x;
    for (int i = tid; i < DOUT * DIN; i += 256) Ws[i] = W[i];
    const int rbase = blockIdx.x * 64;
    for (int i = tid; i < 64 * DIN; i += 256) {
        const int rl = i / DIN, k = i % DIN;
        float v = 0.f;
#pragma unroll
        for (int s2 = 0; s2 < NSUM; ++s2)
            v += src[(long)s2 * NN * DIN + (long)(rbase + rl) * DIN + k];
        Hs[rl][k] = RELU ? fmaxf(v, 0.f) : v;
    }
    __syncthreads();
    const int rl = tid & 63;
    const int c0 = tid >> 6;
    const int r  = rbase + rl;
    const int kk = r & 31;
    const int pidx = (r & ~31) + ((kk & 15) >> 2) * 8 + (kk & 3) + ((kk >> 4) << 2);
    for (int c = c0; c < DOUT; c += 4) {
        float accv = 0.f;
#pragma unroll
        for (int k = 0; k < DIN; ++k) accv += Hs[rl][k] * Ws[c * DIN + k];
        PT[(long)c * NN + pidx] = f2bf_rne(accv);
    }
}

// Final reduce: out[NN][32] = sum_s part[s]
__global__ __launch_bounds__(256) void k_red(
    const float* __restrict__ part, float* __restrict__ out)
{
    const int e = blockIdx.x * 256 + threadIdx.x;
    if (e >= NN * 32 / 4) return;
    fx4 v = (fx4){0.f, 0.f, 0.f, 0.f};
#pragma unroll
    for (int s = 0; s < SK2; ++s)
        v += *(const fx4*)(part + (long)s * NN * 32 + (long)e * 4);
    *(fx4*)(out + (long)e * 4) = v;
}

extern "C" void kernel_launch(void* const* d_in, const int* in_sizes, int n_in,
                              void* d_out, int out_size, void* d_ws, size_t ws_size,
                              hipStream_t stream) {
    const float* A  = (const float*)d_in[0];
    const float* X  = (const float*)d_in[1];
    const float* W1 = (const float*)d_in[2];
    const float* W2 = (const float*)d_in[3];
    const float* W3 = (const float*)d_in[4];
    float* out = (float*)d_out;

    char* ws = (char*)d_ws;
    const size_t part_b = (size_t)SK1 * NN * 64 * 4;   // 64 MiB
    const size_t pt_b   = (size_t)64 * NN * 2;         //  2 MiB
    const size_t abf_b  = (size_t)NN * NN * 2;         // 512 MiB
    float*          part = (float*)ws;
    unsigned short* PT   = (unsigned short*)(ws + part_b);
    unsigned short* Abf  = (unsigned short*)(ws + part_b + pt_b);
    const bool save = ws_size >= part_b + pt_b + abf_b;

    dim3 b(256);
    dim3 gP(NN / 64);
    dim3 g1(NN / 128, SK1);
    dim3 g2(NN / 256, SK2);

    // Layer 1
    k_proj<64, 64, 1, false><<<gP, b, 0, stream>>>(X, W1, PT);
    if (save) k_spmm1<1><<<g1, b, 0, stream>>>(A, Abf, PT, part);
    else      k_spmm1<0><<<g1, b, 0, stream>>>(A, Abf, PT, part);

    // Layer 2
    k_proj<64, 32, SK1, true><<<gP, b, 0, stream>>>(part, W2, PT);
    if (save) k_spmm2<1><<<g2, b, 0, stream>>>(Abf, A, PT, part);
    else      k_spmm2<0><<<g2, b, 0, stream>>>(Abf, A, PT, part);

    // Layer 3
    k_proj<32, 32, SK2, true><<<gP, b, 0, stream>>>(part, W3, PT);
    if (save) k_spmm2<1><<<g2, b, 0, stream>>>(Abf, A, PT, part);
    else      k_spmm2<0><<<g2, b, 0, stream>>>(Abf, A, PT, part);

    k_red<<<dim3(NN * 32 / 4 / 256), b, 0, stream>>>(part, out);
}

// Round 8
// 699.877 us; speedup vs baseline: 3.1723x; 1.2110x over previous
//
#include <hip/hip_runtime.h>
#include <cstdint>
#include <cstddef>

// GCN via associativity: relu((A@H)@W^T) == relu(A@(H@W^T)).
// Per layer: tiny proj PT=(H W^T)^T (bf16, k-slot-permuted) + split-K
// tall-skinny MFMA GEMM part=A@P.
// S1 (this round): LDS-staged. Each block owns 16 rows; global A reads are
// 1KB-contiguous per wave-instruction (was 128B/row/iter -> DRAM row thrash,
// 3.9 TB/s effective). LDS tile stored in MFMA-frag layout == Abf tile layout,
// so frag reads are conflict-free ds_read_b128 and the bf16-A save is a
// linear LDS->global copy. T14 split: issue loads -> compute -> LDS-write.
// S2/S3: round-4 exact (97us each, near ceiling; Abf mostly L3-served).

#define NN 16384
#define SK1 8
#define KC1 (NN / SK1)   // 2048
#define CH 512           // k per staged chunk
#define NCH (KC1 / CH)   // 4
#define SK2 16
#define KC2 (NN / SK2)   // 1024
#define NKB (NN / 32)    // 512 k-blocks

typedef __attribute__((ext_vector_type(8))) short s16x8;
typedef __attribute__((ext_vector_type(4))) float fx4;

__device__ __forceinline__ unsigned short f2bf_rne(float f) {
    unsigned int x = __builtin_bit_cast(unsigned int, f);
    x += 0x7fffu + ((x >> 16) & 1u);
    return (unsigned short)(x >> 16);
}

__device__ __forceinline__ s16x8 pack_bf(fx4 a, fx4 b) {
    s16x8 t;
    t[0] = (short)f2bf_rne(a[0]);
    t[1] = (short)f2bf_rne(a[1]);
    t[2] = (short)f2bf_rne(a[2]);
    t[3] = (short)f2bf_rne(a[3]);
    t[4] = (short)f2bf_rne(b[0]);
    t[5] = (short)f2bf_rne(b[1]);
    t[6] = (short)f2bf_rne(b[2]);
    t[7] = (short)f2bf_rne(b[3]);
    return t;
}

// ---------------------------------------------------------------------------
// S1: part[s] = A@P1 (D=64), LDS-staged. Block = 16 rows x KC1 k.
// grid (NN/16, SK1) = (1024, 8). Wave wv computes col-frag wv (D=64 = 4 frags).
// LDS chunk tile = [16 kblks][64 frag-lanes][8 bf16] (== Abf tile layout),
// XOR-swizzled by ((kblk&7)<<4) on the within-kblk byte offset.
// ---------------------------------------------------------------------------
template <int SAVE>
__global__ __launch_bounds__(256, 4) void k_spmm1(
    const float* __restrict__ A32,
    unsigned short* __restrict__ Abf,        // [NN/16][NKB][64][8] bf16 tiles
    const unsigned short* __restrict__ PT,   // [64][NN] bf16, slot-permuted
    float* __restrict__ part)                // [SK1][NN][64] f32
{
    __shared__ unsigned short Asm[2][16 * 512];   // 2 x 16KB
    const int tid  = threadIdx.x;
    const int lane = tid & 63, wv = tid >> 6;
    const int srow = lane & 15, kg = lane >> 4;
    const int s  = blockIdx.y;
    const int gR = blockIdx.x;               // rowgrp (16 rows)
    const long R = (long)gR * 16;
    const long kbeg = (long)s * KC1;

    fx4 acc = (fx4){0.f, 0.f, 0.f, 0.f};
    fx4 gld[8];

    auto LOADG = [&](int c) {
#pragma unroll
        for (int j = 0; j < 8; ++j) {
            const int u = wv * 8 + j;                    // 0..31: 16 rows x 2 segs
            const int r = u >> 1, seg = u & 1;
            const float* p = A32 + (R + r) * (long)NN + kbeg + (long)c * CH
                             + seg * 256 + lane * 4;     // wave = 1KB dense of one row
            gld[j] = __builtin_nontemporal_load((const fx4*)p);
        }
    };
    auto STORE_LDS = [&](int buf) {
#pragma unroll
        for (int j = 0; j < 8; ++j) {
            const int u = wv * 8 + j;
            const int r = u >> 1, seg = u & 1;
            const int kt = seg * 256 + lane * 4;         // within-chunk k
            const int kblk = kt >> 5;
            const int kb   = kt & 31;
            const int flane = (r & 15) + (((kb & 15) >> 2) << 4);
            const int half  = kb >> 4;
            uint2 v;
            v.x = (unsigned)f2bf_rne(gld[j][0]) | ((unsigned)f2bf_rne(gld[j][1]) << 16);
            v.y = (unsigned)f2bf_rne(gld[j][2]) | ((unsigned)f2bf_rne(gld[j][3]) << 16);
            const int boff = kblk * 1024 + ((flane * 16 + half * 8) ^ ((kblk & 7) << 4));
            *(uint2*)((char*)&Asm[buf][0] + boff) = v;
        }
    };
    auto COMPUTE = [&](int buf, int c) {
#pragma unroll
        for (int ks = 0; ks < 16; ++ks) {
            const int aoff = ks * 1024 + ((lane * 16) ^ ((ks & 7) << 4));
            s16x8 af = *(const s16x8*)((const char*)&Asm[buf][0] + aoff);
            s16x8 bf = *(const s16x8*)(PT + (long)(wv * 16 + srow) * NN + kbeg
                                       + (long)c * CH + ks * 32 + kg * 8);
            acc = __builtin_amdgcn_mfma_f32_16x16x32_bf16(af, bf, acc, 0, 0, 0);
        }
        if (SAVE) {
            const long kb0 = (kbeg + (long)c * CH) >> 5;
#pragma unroll
            for (int t = 0; t < 4; ++t) {
                const int kblk = wv * 4 + t;
                const int aoff = kblk * 1024 + ((lane * 16) ^ ((kblk & 7) << 4));
                s16x8 v = *(const s16x8*)((const char*)&Asm[buf][0] + aoff);
                *(s16x8*)(Abf + (((long)gR * NKB + kb0 + kblk) * 64 + lane) * 8) = v;
            }
        }
    };

    LOADG(0);
    STORE_LDS(0);
    __syncthreads();
    for (int c = 0; c < NCH; ++c) {
        if (c + 1 < NCH) LOADG(c + 1);       // issue early (T14)
        COMPUTE(c & 1, c);
        if (c + 1 < NCH) STORE_LDS((c + 1) & 1);
        __syncthreads();
    }

    // C layout: col = lane&15, row = (lane>>4)*4 + reg
    float* pb = part + (long)s * NN * 64 + R * 64;
#pragma unroll
    for (int r = 0; r < 4; ++r)
        pb[(kg * 4 + r) * 64 + wv * 16 + srow] = acc[r];
}

// ---------------------------------------------------------------------------
// S2/S3: part[s] = A@P (D=32). 4 row-tiles/wave, frag-tiled bf16 A (round-4).
// ---------------------------------------------------------------------------
template <int ABF>
__global__ __launch_bounds__(256, 4) void k_spmm2(
    const unsigned short* __restrict__ Abf,
    const float* __restrict__ A32,
    const unsigned short* __restrict__ PT,   // [32][NN]
    float* __restrict__ part)                // [SK2][NN][32]
{
    const int lane = threadIdx.x & 63;
    const int wv   = threadIdx.x >> 6;
    const int srow = lane & 15;
    const int kg   = lane >> 4;
    const int s    = blockIdx.y;
    const long kbeg = (long)s * KC2;
    const int rowbase = blockIdx.x * 256 + wv * 64;
    const long g0 = rowbase >> 4;

    fx4 acc[4][2];
#pragma unroll
    for (int t = 0; t < 4; ++t)
#pragma unroll
        for (int c = 0; c < 2; ++c) acc[t][c] = (fx4){0.f, 0.f, 0.f, 0.f};

#pragma unroll 2
    for (int i = 0; i < KC2 / 32; ++i) {
        const long ko = kbeg + (long)i * 32;
        const long kblk = ko >> 5;
        s16x8 af[4];
        if (ABF) {
#pragma unroll
            for (int t = 0; t < 4; ++t)
                af[t] = *(const s16x8*)(Abf + (((g0 + t) * NKB + kblk) * 64 + lane) * 8);
        } else {
#pragma unroll
            for (int t = 0; t < 4; ++t) {
                const float* p = A32 + (long)(rowbase + t * 16 + srow) * NN + ko + kg * 4;
                fx4 a0 = __builtin_nontemporal_load((const fx4*)p);
                fx4 a1 = __builtin_nontemporal_load((const fx4*)(p + 16));
                af[t] = pack_bf(a0, a1);
            }
        }
        s16x8 b0 = *(const s16x8*)(PT + (long)srow * NN + ko + kg * 8);
        s16x8 b1 = *(const s16x8*)(PT + (long)(16 + srow) * NN + ko + kg * 8);
#pragma unroll
        for (int t = 0; t < 4; ++t) {
            acc[t][0] = __builtin_amdgcn_mfma_f32_16x16x32_bf16(af[t], b0, acc[t][0], 0, 0, 0);
            acc[t][1] = __builtin_amdgcn_mfma_f32_16x16x32_bf16(af[t], b1, acc[t][1], 0, 0, 0);
        }
    }
    float* pbase = part + (long)s * NN * 32;
#pragma unroll
    for (int t = 0; t < 4; ++t)
#pragma unroll
        for (int c = 0; c < 2; ++c)
#pragma unroll
            for (int r = 0; r < 4; ++r)
                pbase[(long)(rowbase + t * 16 + kg * 4 + r) * 32 + c * 16 + srow] = acc[t][c][r];
}

// ---------------------------------------------------------------------------
// Projection: PT[c][perm(r)] = bf16( act(H[r,:]) @ W[c,:] )
// ---------------------------------------------------------------------------
template <int DIN, int DOUT, int NSUM, bool RELU>
__global__ __launch_bounds__(256) void k_proj(
    const float* __restrict__ src,     // [NSUM][NN][DIN]
    const float* __restrict__ W,       // [DOUT][DIN]
    unsigned short* __restrict__ PT)   // [DOUT][NN] slot-permuted
{
    __shared__ float Ws[DOUT * DIN];
    __shared__ float Hs[64][DIN + 1];
    const int tid = threadIdx.x;
    for (int i = tid; i < DOUT * DIN; i += 256) Ws[i] = W[i];
    const int rbase = blockIdx.x * 64;
    for (int i = tid; i < 64 * DIN; i += 256) {
        const int rl = i / DIN, k = i % DIN;
        float v = 0.f;
#pragma unroll
        for (int s2 = 0; s2 < NSUM; ++s2)
            v += src[(long)s2 * NN * DIN + (long)(rbase + rl) * DIN + k];
        Hs[rl][k] = RELU ? fmaxf(v, 0.f) : v;
    }
    __syncthreads();
    const int rl = tid & 63;
    const int c0 = tid >> 6;
    const int r  = rbase + rl;
    const int kk = r & 31;
    const int pidx = (r & ~31) + ((kk & 15) >> 2) * 8 + (kk & 3) + ((kk >> 4) << 2);
    for (int c = c0; c < DOUT; c += 4) {
        float accv = 0.f;
#pragma unroll
        for (int k = 0; k < DIN; ++k) accv += Hs[rl][k] * Ws[c * DIN + k];
        PT[(long)c * NN + pidx] = f2bf_rne(accv);
    }
}

// Final reduce: out[NN][32] = sum_s part[s]
__global__ __launch_bounds__(256) void k_red(
    const float* __restrict__ part, float* __restrict__ out)
{
    const int e = blockIdx.x * 256 + threadIdx.x;
    if (e >= NN * 32 / 4) return;
    fx4 v = (fx4){0.f, 0.f, 0.f, 0.f};
#pragma unroll
    for (int s = 0; s < SK2; ++s)
        v += *(const fx4*)(part + (long)s * NN * 32 + (long)e * 4);
    *(fx4*)(out + (long)e * 4) = v;
}

extern "C" void kernel_launch(void* const* d_in, const int* in_sizes, int n_in,
                              void* d_out, int out_size, void* d_ws, size_t ws_size,
                              hipStream_t stream) {
    const float* A  = (const float*)d_in[0];
    const float* X  = (const float*)d_in[1];
    const float* W1 = (const float*)d_in[2];
    const float* W2 = (const float*)d_in[3];
    const float* W3 = (const float*)d_in[4];
    float* out = (float*)d_out;

    char* ws = (char*)d_ws;
    const size_t part_b = (size_t)SK1 * NN * 64 * 4;   // 32 MiB (== SK2*NN*32*4)
    const size_t pt_b   = (size_t)64 * NN * 2;         //  2 MiB
    const size_t abf_b  = (size_t)NN * NN * 2;         // 512 MiB
    float*          part = (float*)ws;
    unsigned short* PT   = (unsigned short*)(ws + part_b);
    unsigned short* Abf  = (unsigned short*)(ws + part_b + pt_b);
    const bool save = ws_size >= part_b + pt_b + abf_b;

    dim3 b(256);
    dim3 gP(NN / 64);
    dim3 g1(NN / 16, SK1);
    dim3 g2(NN / 256, SK2);

    // Layer 1
    k_proj<64, 64, 1, false><<<gP, b, 0, stream>>>(X, W1, PT);
    if (save) k_spmm1<1><<<g1, b, 0, stream>>>(A, Abf, PT, part);
    else      k_spmm1<0><<<g1, b, 0, stream>>>(A, Abf, PT, part);

    // Layer 2
    k_proj<64, 32, SK1, true><<<gP, b, 0, stream>>>(part, W2, PT);
    if (save) k_spmm2<1><<<g2, b, 0, stream>>>(Abf, A, PT, part);
    else      k_spmm2<0><<<g2, b, 0, stream>>>(Abf, A, PT, part);

    // Layer 3
    k_proj<32, 32, SK2, true><<<gP, b, 0, stream>>>(part, W3, PT);
    if (save) k_spmm2<1><<<g2, b, 0, stream>>>(Abf, A, PT, part);
    else      k_spmm2<0><<<g2, b, 0, stream>>>(Abf, A, PT, part);

    k_red<<<dim3(NN * 32 / 4 / 256), b, 0, stream>>>(part, out);
}

// Round 9
// 694.474 us; speedup vs baseline: 3.1970x; 1.0078x over previous
//
#include <hip/hip_runtime.h>
#include <cstdint>
#include <cstddef>

// GCN via associativity: relu((A@H)@W^T) == relu(A@(H@W^T)).
// Per layer: tiny proj PT=(H W^T)^T (bf16, k-slot-permuted) + split-K
// tall-skinny MFMA GEMM part=A@P.
// S1 (this round): async global_load_lds pipeline. Round-8 proved granule
// is not the limiter; Little's law says ~9.2KB/CU must be in flight, reg
// staging held ~2KB. gld_lds stages a full 16KB fp32 chunk per block with
// counted completion at the barrier (m97 2-phase), no VGPR round-trip.
// Source lanes pre-swizzled (lane^(row&7) on 16B slots, m173) so the
// LDS frag reads are bank-conflict-free; fp32->bf16 on LDS->reg read feeds
// both MFMA and the Abf tile save (deduped: wave wv saves ks=2wv,2wv+1).
// S2/S3: round-4 exact (97us each; Abf mostly L3-served).

#define NN 16384
#define SK1 8
#define KC1 (NN / SK1)   // 2048
#define CH 256           // k per staged chunk (16 rows x 256 k x 4B = 16KB LDS)
#define NCH (KC1 / CH)   // 8
#define SK2 16
#define KC2 (NN / SK2)   // 1024
#define NKB (NN / 32)    // 512 k-blocks

typedef __attribute__((ext_vector_type(8))) short s16x8;
typedef __attribute__((ext_vector_type(4))) float fx4;

__device__ __forceinline__ unsigned short f2bf_rne(float f) {
    unsigned int x = __builtin_bit_cast(unsigned int, f);
    x += 0x7fffu + ((x >> 16) & 1u);
    return (unsigned short)(x >> 16);
}

__device__ __forceinline__ s16x8 pack_bf(fx4 a, fx4 b) {
    s16x8 t;
    t[0] = (short)f2bf_rne(a[0]);
    t[1] = (short)f2bf_rne(a[1]);
    t[2] = (short)f2bf_rne(a[2]);
    t[3] = (short)f2bf_rne(a[3]);
    t[4] = (short)f2bf_rne(b[0]);
    t[5] = (short)f2bf_rne(b[1]);
    t[6] = (short)f2bf_rne(b[2]);
    t[7] = (short)f2bf_rne(b[3]);
    return t;
}

__device__ __forceinline__ void gload_lds16(const float* g, float* l) {
    __builtin_amdgcn_global_load_lds(
        (const __attribute__((address_space(1))) void*)g,
        (__attribute__((address_space(3))) void*)l, 16, 0, 0);
}

// ---------------------------------------------------------------------------
// S1: part[s] = A@P1 (D=64), gld_lds-staged. Block = 16 rows x KC1 k.
// grid (NN/16, SK1). Wave wv computes col-frag wv; all waves read all ks.
// LDS: fp32 [16 rows][256 k], row slot w (16B units) holds global slot
// w ^ (row&7) (pre-swizzled source) -> frag ds_read_b128 conflict-free.
// ---------------------------------------------------------------------------
template <int SAVE>
__global__ __launch_bounds__(256, 4) void k_spmm1(
    const float* __restrict__ A32,
    unsigned short* __restrict__ Abf,        // [NN/16][NKB][64][8] bf16 tiles
    const unsigned short* __restrict__ PT,   // [64][NN] bf16, slot-permuted
    float* __restrict__ part)                // [SK1][NN][64] f32
{
    __shared__ float Asm[2][16 * CH];        // 2 x 16KB
    const int tid  = threadIdx.x;
    const int lane = tid & 63, wv = tid >> 6;
    const int srow = lane & 15, kg = lane >> 4;
    const int s  = blockIdx.y;
    const int gR = blockIdx.x;               // rowgrp (16 rows)
    const long R = (long)gR * 16;
    const long kbeg = (long)s * KC1;

    fx4 acc = (fx4){0.f, 0.f, 0.f, 0.f};

    auto STAGE = [&](int buf, int c) {
#pragma unroll
        for (int j = 0; j < 4; ++j) {
            const int r = wv * 4 + j;                       // wave-uniform row
            const int sl = lane ^ (r & 7);                  // swizzled 16B slot
            const float* g = A32 + (R + r) * (long)NN + kbeg + (long)c * CH + sl * 4;
            gload_lds16(g, &Asm[buf][r * CH]);              // dest wave-uniform
        }
    };
    auto COMPUTE = [&](int buf, int c) {
        const long kb0 = (kbeg + (long)c * CH) >> 5;
        const float* rowp = &Asm[buf][srow * CH];
#pragma unroll
        for (int ks = 0; ks < CH / 32; ++ks) {
            const int s0 = ((ks * 8 + kg) ^ (srow & 7)) * 4;       // fp32 idx
            const int s1 = ((ks * 8 + 4 + kg) ^ (srow & 7)) * 4;
            fx4 a0 = *(const fx4*)(rowp + s0);
            fx4 a1 = *(const fx4*)(rowp + s1);
            s16x8 af = pack_bf(a0, a1);
            s16x8 bf = *(const s16x8*)(PT + (long)(wv * 16 + srow) * NN + kbeg
                                       + (long)c * CH + ks * 32 + kg * 8);
            acc = __builtin_amdgcn_mfma_f32_16x16x32_bf16(af, bf, acc, 0, 0, 0);
            if (SAVE && (ks >> 1) == wv)    // wave wv owns ks = 2wv, 2wv+1
                *(s16x8*)(Abf + (((long)gR * NKB + kb0 + ks) * 64 + lane) * 8) = af;
        }
    };

    STAGE(0, 0);
    __syncthreads();
    for (int c = 0; c < NCH; ++c) {
        if (c + 1 < NCH) STAGE((c + 1) & 1, c + 1);   // async, in flight across compute
        COMPUTE(c & 1, c);
        __syncthreads();                              // drains vmcnt -> next buf ready
    }

    // C layout: col = lane&15, row = (lane>>4)*4 + reg
    float* pb = part + (long)s * NN * 64 + R * 64;
#pragma unroll
    for (int r = 0; r < 4; ++r)
        pb[(kg * 4 + r) * 64 + wv * 16 + srow] = acc[r];
}

// ---------------------------------------------------------------------------
// S2/S3: part[s] = A@P (D=32). 4 row-tiles/wave, frag-tiled bf16 A (round-4).
// ---------------------------------------------------------------------------
template <int ABF>
__global__ __launch_bounds__(256, 4) void k_spmm2(
    const unsigned short* __restrict__ Abf,
    const float* __restrict__ A32,
    const unsigned short* __restrict__ PT,   // [32][NN]
    float* __restrict__ part)                // [SK2][NN][32]
{
    const int lane = threadIdx.x & 63;
    const int wv   = threadIdx.x >> 6;
    const int srow = lane & 15;
    const int kg   = lane >> 4;
    const int s    = blockIdx.y;
    const long kbeg = (long)s * KC2;
    const int rowbase = blockIdx.x * 256 + wv * 64;
    const long g0 = rowbase >> 4;

    fx4 acc[4][2];
#pragma unroll
    for (int t = 0; t < 4; ++t)
#pragma unroll
        for (int c = 0; c < 2; ++c) acc[t][c] = (fx4){0.f, 0.f, 0.f, 0.f};

#pragma unroll 2
    for (int i = 0; i < KC2 / 32; ++i) {
        const long ko = kbeg + (long)i * 32;
        const long kblk = ko >> 5;
        s16x8 af[4];
        if (ABF) {
#pragma unroll
            for (int t = 0; t < 4; ++t)
                af[t] = *(const s16x8*)(Abf + (((g0 + t) * NKB + kblk) * 64 + lane) * 8);
        } else {
#pragma unroll
            for (int t = 0; t < 4; ++t) {
                const float* p = A32 + (long)(rowbase + t * 16 + srow) * NN + ko + kg * 4;
                fx4 a0 = __builtin_nontemporal_load((const fx4*)p);
                fx4 a1 = __builtin_nontemporal_load((const fx4*)(p + 16));
                af[t] = pack_bf(a0, a1);
            }
        }
        s16x8 b0 = *(const s16x8*)(PT + (long)srow * NN + ko + kg * 8);
        s16x8 b1 = *(const s16x8*)(PT + (long)(16 + srow) * NN + ko + kg * 8);
#pragma unroll
        for (int t = 0; t < 4; ++t) {
            acc[t][0] = __builtin_amdgcn_mfma_f32_16x16x32_bf16(af[t], b0, acc[t][0], 0, 0, 0);
            acc[t][1] = __builtin_amdgcn_mfma_f32_16x16x32_bf16(af[t], b1, acc[t][1], 0, 0, 0);
        }
    }
    float* pbase = part + (long)s * NN * 32;
#pragma unroll
    for (int t = 0; t < 4; ++t)
#pragma unroll
        for (int c = 0; c < 2; ++c)
#pragma unroll
            for (int r = 0; r < 4; ++r)
                pbase[(long)(rowbase + t * 16 + kg * 4 + r) * 32 + c * 16 + srow] = acc[t][c][r];
}

// ---------------------------------------------------------------------------
// Projection: PT[c][perm(r)] = bf16( act(H[r,:]) @ W[c,:] )
// ---------------------------------------------------------------------------
template <int DIN, int DOUT, int NSUM, bool RELU>
__global__ __launch_bounds__(256) void k_proj(
    const float* __restrict__ src,     // [NSUM][NN][DIN]
    const float* __restrict__ W,       // [DOUT][DIN]
    unsigned short* __restrict__ PT)   // [DOUT][NN] slot-permuted
{
    __shared__ float Ws[DOUT * DIN];
    __shared__ float Hs[64][DIN + 1];
    const int tid = threadIdx.x;
    for (int i = tid; i < DOUT * DIN; i += 256) Ws[i] = W[i];
    const int rbase = blockIdx.x * 64;
    for (int i = tid; i < 64 * DIN; i += 256) {
        const int rl = i / DIN, k = i % DIN;
        float v = 0.f;
#pragma unroll
        for (int s2 = 0; s2 < NSUM; ++s2)
            v += src[(long)s2 * NN * DIN + (long)(rbase + rl) * DIN + k];
        Hs[rl][k] = RELU ? fmaxf(v, 0.f) : v;
    }
    __syncthreads();
    const int rl = tid & 63;
    const int c0 = tid >> 6;
    const int r  = rbase + rl;
    const int kk = r & 31;
    const int pidx = (r & ~31) + ((kk & 15) >> 2) * 8 + (kk & 3) + ((kk >> 4) << 2);
    for (int c = c0; c < DOUT; c += 4) {
        float accv = 0.f;
#pragma unroll
        for (int k = 0; k < DIN; ++k) accv += Hs[rl][k] * Ws[c * DIN + k];
        PT[(long)c * NN + pidx] = f2bf_rne(accv);
    }
}

// Final reduce: out[NN][32] = sum_s part[s]
__global__ __launch_bounds__(256) void k_red(
    const float* __restrict__ part, float* __restrict__ out)
{
    const int e = blockIdx.x * 256 + threadIdx.x;
    if (e >= NN * 32 / 4) return;
    fx4 v = (fx4){0.f, 0.f, 0.f, 0.f};
#pragma unroll
    for (int s = 0; s < SK2; ++s)
        v += *(const fx4*)(part + (long)s * NN * 32 + (long)e * 4);
    *(fx4*)(out + (long)e * 4) = v;
}

extern "C" void kernel_launch(void* const* d_in, const int* in_sizes, int n_in,
                              void* d_out, int out_size, void* d_ws, size_t ws_size,
                              hipStream_t stream) {
    const float* A  = (const float*)d_in[0];
    const float* X  = (const float*)d_in[1];
    const float* W1 = (const float*)d_in[2];
    const float* W2 = (const float*)d_in[3];
    const float* W3 = (const float*)d_in[4];
    float* out = (float*)d_out;

    char* ws = (char*)d_ws;
    const size_t part_b = (size_t)SK1 * NN * 64 * 4;   // 32 MiB (== SK2*NN*32*4)
    const size_t pt_b   = (size_t)64 * NN * 2;         //  2 MiB
    const size_t abf_b  = (size_t)NN * NN * 2;         // 512 MiB
    float*          part = (float*)ws;
    unsigned short* PT   = (unsigned short*)(ws + part_b);
    unsigned short* Abf  = (unsigned short*)(ws + part_b + pt_b);
    const bool save = ws_size >= part_b + pt_b + abf_b;

    dim3 b(256);
    dim3 gP(NN / 64);
    dim3 g1(NN / 16, SK1);
    dim3 g2(NN / 256, SK2);

    // Layer 1
    k_proj<64, 64, 1, false><<<gP, b, 0, stream>>>(X, W1, PT);
    if (save) k_spmm1<1><<<g1, b, 0, stream>>>(A, Abf, PT, part);
    else      k_spmm1<0><<<g1, b, 0, stream>>>(A, Abf, PT, part);

    // Layer 2
    k_proj<64, 32, SK1, true><<<gP, b, 0, stream>>>(part, W2, PT);
    if (save) k_spmm2<1><<<g2, b, 0, stream>>>(Abf, A, PT, part);
    else      k_spmm2<0><<<g2, b, 0, stream>>>(Abf, A, PT, part);

    // Layer 3
    k_proj<32, 32, SK2, true><<<gP, b, 0, stream>>>(part, W3, PT);
    if (save) k_spmm2<1><<<g2, b, 0, stream>>>(Abf, A, PT, part);
    else      k_spmm2<0><<<g2, b, 0, stream>>>(Abf, A, PT, part);

    k_red<<<dim3(NN * 32 / 4 / 256), b, 0, stream>>>(part, out);
}